// Round 6
// baseline (149.785 us; speedup 1.0000x reference)
//
#include <hip/hip_runtime.h>
#include <hip/hip_bf16.h>

#define NB 4
#define NC 128
#define NH 128
#define NW 240
#define NE 64
#define NK 9
#define PLANE (NH*NW)        // 30720: stride between channels
#define CHW (NC*PLANE)

typedef __attribute__((ext_vector_type(8))) short short8;
typedef __attribute__((ext_vector_type(4))) float f32x4;
typedef __attribute__((ext_vector_type(2))) __fp16 fp16x2;
typedef __attribute__((ext_vector_type(8))) __fp16 fp16x8;

__device__ __forceinline__ unsigned pkh(float x, float y){
  fp16x2 h = __builtin_amdgcn_cvt_pkrtz(x, y);
  return __builtin_bit_cast(unsigned, h);
}
__device__ __forceinline__ float fdot2u(unsigned a, unsigned b, float c){
#if __has_builtin(__builtin_amdgcn_fdot2)
  return __builtin_amdgcn_fdot2(__builtin_bit_cast(fp16x2,a),
                                __builtin_bit_cast(fp16x2,b), c, false);
#else
  fp16x2 ha = __builtin_bit_cast(fp16x2,a), hb = __builtin_bit_cast(fp16x2,b);
  return c + (float)ha[0]*(float)hb[0] + (float)ha[1]*(float)hb[1];
#endif
}
__device__ __forceinline__ int swz(int r){ return (r ^ (r>>3)) & 7; }

// async global->LDS, 16 B per lane. g: per-lane global addr (16B aligned);
// lds_u: wave-uniform LDS base; HW adds lane*16.
__device__ __forceinline__ void gload_lds16(const float* g, float* lds_u, int lane){
#if __has_builtin(__builtin_amdgcn_global_load_lds)
  __builtin_amdgcn_global_load_lds(
      (const __attribute__((address_space(1))) unsigned*)g,
      (__attribute__((address_space(3))) unsigned*)lds_u, 16, 0, 0);
#else
  *(float4*)(lds_u + 4*lane) = *(const float4*)g;   // sync fallback
#endif
}

// ======================================================================
// Fused kernel, DMA-staged: one block per (b,h) row. 512 blocks x 1024 thr.
// LDS: xs0/xs1 (fp32 32-ch chunk dbuf, 2x30,720 B) + phis fp16 17,408 B
//      = 78,848 B -> 2 blocks/CU. 8 chunk-rounds (L0..3, R0..3):
//   __syncthreads (vmcnt(0) drains exactly the chunk to consume)
//   -> issue DMA for chunk k+1 (flies the whole round, zero VGPR cost)
//   -> MFMA on chunk k (fp32 LDS read + cvt folded into bv build).
// Epilogue: FLb aliases xs0, FRb aliases xs1, cvb aliases phis.
// ======================================================================
__global__ __launch_bounds__(1024, 8)
void fused_kernel(const float* __restrict__ xL,
                  const float* __restrict__ xR,
                  const float* __restrict__ d0g,
                  const float* __restrict__ phig,
                  float* __restrict__ outg)
{
  __shared__ __attribute__((aligned(16))) float xs0[7680];              // 30,720 B
  __shared__ __attribute__((aligned(16))) float xs1[7680];              // 30,720 B
  __shared__ __attribute__((aligned(16))) unsigned short phis[NE*136];  // 17,408 B

  const int tid  = threadIdx.x;
  const int lane = tid & 63;
  const int wv   = tid >> 6;
  const int b    = blockIdx.x >> 7;
  const int h    = blockIdx.x & 127;
  const size_t base = (size_t)b*CHW + (size_t)h*NW;
  const int pixbase = (b*NH + h)*NW;

  const int mrow = lane & 15;
  const int kg   = lane >> 4;
  const int nt   = wv;                 // 16 waves, nt<15 active
  const int n    = 16*nt + mrow;       // owned pixel column

  // chunk q (0..7): side = q<4 ? L : R, channels 32*(q&3).., buffer q&1.
  auto issue_chunk = [&](int q){
    const float* src = (q < 4) ? xL : xR;
    const int cb = 32*(q & 3);
    float* buf = (q & 1) ? xs1 : xs0;
    #pragma unroll
    for (int i = 0; i < 2; ++i) {
      int qq = 2*wv + i;               // wave-instr id, 30 per chunk
      if (qq < 30) {
        int g4 = qq*64 + lane;         // float4 id 0..1919
        int c = g4/60, s4 = g4 - 60*c; // channel, f4-within-row
        gload_lds16(src + base + (size_t)(cb + c)*PLANE + 4*s4,
                    buf + qq*256, lane);
      }
    }
  };

  auto gemm_round = [&](const float* bf, int cb, f32x4 (&acc)[4]){
    if (nt < 15) {
      fp16x8 bv;
      #pragma unroll
      for (int j = 0; j < 8; ++j)
        bv[j] = (__fp16)bf[(8*kg + j)*240 + n];
      #pragma unroll
      for (int mt = 0; mt < 4; ++mt) {
        short8 raw = *(const short8*)&phis[(16*mt + mrow)*136 + cb + 8*kg];
        fp16x8 af = __builtin_bit_cast(fp16x8, raw);
        acc[mt] = __builtin_amdgcn_mfma_f32_16x16x32_f16(af, bv, acc[mt], 0, 0, 0);
      }
    }
  };

  auto norm_pack = [&](f32x4 (&acc)[4], uint2 (&pk)[4]){
    float ss = 0.f;
    #pragma unroll
    for (int mt = 0; mt < 4; ++mt)
      #pragma unroll
      for (int r = 0; r < 4; ++r)
        ss += acc[mt][r]*acc[mt][r];
    ss += __shfl_xor(ss, 16, 64);
    ss += __shfl_xor(ss, 32, 64);
    float inv = 1.f/(sqrtf(ss) + 1e-6f);
    #pragma unroll
    for (int mt = 0; mt < 4; ++mt) {
      pk[mt].x = pkh(acc[mt][0]*inv, acc[mt][1]*inv);
      pk[mt].y = pkh(acc[mt][2]*inv, acc[mt][3]*inv);
    }
  };

  auto frag_write = [&](unsigned short* dst, uint2 (&pk)[4]){
    #pragma unroll
    for (int mt = 0; mt < 4; ++mt) {
      int e0 = 16*mt + 4*kg;
      int pos = n*64 + (((e0>>3) ^ swz(n))<<3) + (e0&7);
      *(uint2*)&dst[pos] = pk[mt];
    }
  };

  // ---- prologue: start chunk0 DMA, then stage phi + d0 ----
  issue_chunk(0);
  float d0v = (tid < 960) ? d0g[pixbase + (tid >> 2)] : 0.f;
  float4 pr[2];
  #pragma unroll
  for (int i = 0; i < 2; ++i) {
    int idx = i*1024 + tid;
    pr[i] = *(const float4*)(phig + (idx>>5)*128 + 4*(idx&31));
  }
  #pragma unroll
  for (int i = 0; i < 2; ++i) {
    int idx = i*1024 + tid;
    uint2 pk; pk.x = pkh(pr[i].x, pr[i].y); pk.y = pkh(pr[i].z, pr[i].w);
    *(uint2*)&phis[(idx>>5)*136 + 4*(idx&31)] = pk;
  }

  f32x4 accL[4], accR[4];
  #pragma unroll
  for (int mt = 0; mt < 4; ++mt) {
    accL[mt] = (f32x4){0.f,0.f,0.f,0.f};
    accR[mt] = (f32x4){0.f,0.f,0.f,0.f};
  }
  uint2 flpk[4], frpk[4];

  // ---- 8 chunk-rounds ----
  __syncthreads();  issue_chunk(1);  gemm_round(xs0,  0, accL);
  __syncthreads();  issue_chunk(2);  gemm_round(xs1, 32, accL);
  __syncthreads();  issue_chunk(3);  gemm_round(xs0, 64, accL);
  __syncthreads();  issue_chunk(4);  gemm_round(xs1, 96, accL);
  if (nt < 15) norm_pack(accL, flpk);
  __syncthreads();  issue_chunk(5);  gemm_round(xs0,  0, accR);
  __syncthreads();  issue_chunk(6);  gemm_round(xs1, 32, accR);
  __syncthreads();  issue_chunk(7);  gemm_round(xs0, 64, accR);
  __syncthreads();
  // round 7: xs0 free (last read was chunk 6) -> write FL frags there
  unsigned short* FLb = (unsigned short*)xs0;   // 240x64 fp16, swizzled
  if (nt < 15) frag_write(FLb, flpk);
  gemm_round(xs1, 96, accR);
  if (nt < 15) norm_pack(accR, frpk);
  __syncthreads();
  unsigned short* FRb = (unsigned short*)xs1;
  if (nt < 15) frag_write(FRb, frpk);
  __syncthreads();

  // ---- cost (p = tid>>2, 4-way e-split, fdot2) ----
  float* cvb = (float*)phis;           // 8,640 B <= 17,408; phis reads done
  if (tid < 960) {
    const int p  = tid >> 2;
    const int eh = tid & 3;
    float xf  = (float)p - d0v;
    float x0  = floorf(xf);
    float wfr = xf - x0;
    int jb = (int)x0 - 4;

    unsigned fl[8];
    #pragma unroll
    for (int i = 0; i < 2; ++i) {
      int c4 = 2*eh + i;
      uint4 raw = *(const uint4*)&FLb[p*64 + ((c4 ^ swz(p))<<3)];
      fl[4*i+0]=raw.x; fl[4*i+1]=raw.y; fl[4*i+2]=raw.z; fl[4*i+3]=raw.w;
    }

    float D[10];
    #pragma unroll
    for (int t = 0; t < 10; ++t) {
      int j = jb + t;
      j = j < 0 ? 0 : (j > NW-1 ? NW-1 : j);
      float s = 0.f;
      #pragma unroll
      for (int i = 0; i < 2; ++i) {
        int c4 = 2*eh + i;
        uint4 raw = *(const uint4*)&FRb[j*64 + ((c4 ^ swz(j))<<3)];
        s = fdot2u(fl[4*i+0], raw.x, s);
        s = fdot2u(fl[4*i+1], raw.y, s);
        s = fdot2u(fl[4*i+2], raw.z, s);
        s = fdot2u(fl[4*i+3], raw.w, s);
      }
      D[t] = s;
    }
    #pragma unroll
    for (int t = 0; t < 10; ++t) {
      D[t] += __shfl_xor(D[t], 1, 64);
      D[t] += __shfl_xor(D[t], 2, 64);
    }

    #define WK(k) { const int t0 = 8-(k); cvb[(k)*NW + p] = (1.f - wfr)*D[t0] + wfr*D[t0+1]; }
    if      (eh == 0) { WK(0) WK(1) WK(2) }
    else if (eh == 1) { WK(3) WK(4) }
    else if (eh == 2) { WK(5) WK(6) }
    else              { WK(7) WK(8) }
    #undef WK
  }
  __syncthreads();

  // ---- coalesced out store: 540 float4 (9 k-planes x 60) ----
  if (tid < 540) {
    int k = tid/60, w4 = tid - 60*k;
    float4 v = *(const float4*)&cvb[k*NW + 4*w4];
    *(float4*)(outg + (size_t)b*NK*PLANE + (size_t)h*NW + (size_t)k*PLANE + 4*w4) = v;
  }
}

extern "C" void kernel_launch(void* const* d_in, const int* in_sizes, int n_in,
                              void* d_out, int out_size, void* d_ws, size_t ws_size,
                              hipStream_t stream) {
  const float* xL   = (const float*)d_in[0];
  const float* xR   = (const float*)d_in[1];
  const float* d0g  = (const float*)d_in[2];
  const float* phig = (const float*)d_in[3];
  float* outg = (float*)d_out;
  fused_kernel<<<dim3(NB*NH), dim3(1024), 0, stream>>>(xL, xR, d0g, phig, outg);
}